// Round 3
// baseline (1312.136 us; speedup 1.0000x reference)
//
#include <hip/hip_runtime.h>
#include <hip/hip_bf16.h>
#include <cstdint>
#include <cstddef>

#define NEG_INF (-1.0e9f)

typedef __attribute__((ext_vector_type(8))) short bf16x8;
typedef __attribute__((ext_vector_type(4))) float f32x4;

constexpr int BB = 64;     // batch
constexpr int NN = 2048;   // seq len
constexpr int HH = 512;    // h dim
constexpr int DD = 512;    // enc dim (GEMM K)
constexpr int AA = 512;    // attention dim (GEMM N)

__device__ __forceinline__ float fast_rcp(float x) {
#if __has_builtin(__builtin_amdgcn_rcpf)
  return __builtin_amdgcn_rcpf(x);
#else
  return 1.f / x;
#endif
}

__device__ __forceinline__ float fast_tanh(float x) {
  float e = __expf(2.f * fabsf(x));
  float t = 1.f - 2.f * fast_rcp(e + 1.f);
  return copysignf(t, x);
}

// 8 fp32 -> bf16x8 via packed HW cvt
__device__ __forceinline__ bf16x8 pack8(const float4& lo, const float4& hi) {
  __hip_bfloat162 a = __float22bfloat162_rn(float2{lo.x, lo.y});
  __hip_bfloat162 b = __float22bfloat162_rn(float2{lo.z, lo.w});
  __hip_bfloat162 c = __float22bfloat162_rn(float2{hi.x, hi.y});
  __hip_bfloat162 d = __float22bfloat162_rn(float2{hi.z, hi.w});
  union { unsigned int w[4]; bf16x8 v; } u;
  __builtin_memcpy(&u.w[0], &a, 4);
  __builtin_memcpy(&u.w[1], &b, 4);
  __builtin_memcpy(&u.w[2], &c, 4);
  __builtin_memcpy(&u.w[3], &d, 4);
  return u.v;
}

// -------- We -> bf16, packed into MFMA B-fragment tiles --------
// Tile (jc,kg) = cols [jc*16,+16) x k [kg*32,+32), stored as 512 ushorts at
// web[(jc*16+kg)*512], element order = lane-major: lane l holds
// We[jc*16 + (l&15)][kg*32 + (l>>4)*8 + e], e=0..7, at tile_off + l*8.
// A B-fragment load is then one fully-coalesced 1 KB wave read.
__global__ __launch_bounds__(256)
void we_cast_kernel(const float* __restrict__ We, unsigned short* __restrict__ web) {
  const int gid  = blockIdx.x * 256 + threadIdx.x;   // 32768 total
  const int l    = gid & 63;
  const int tile = gid >> 6;        // 0..511
  const int jc   = tile >> 4;       // col-group 0..31
  const int kg   = tile & 15;       // k-group  0..15
  const float* src = We + (size_t)(jc * 16 + (l & 15)) * DD + kg * 32 + (l >> 4) * 8;
  float4 s0 = *(const float4*)src;
  float4 s1 = *(const float4*)(src + 4);
  *(bf16x8*)(web + (size_t)tile * 512 + l * 8) = pack8(s0, s1);
}

// -------- proj_h --------
__global__ __launch_bounds__(256)
void proj_h_kernel(const float* __restrict__ h, const float* __restrict__ Wh,
                   float* __restrict__ ph) {
  __shared__ float hL[HH];
  const int b = blockIdx.x;
  hL[threadIdx.x]       = h[b * HH + threadIdx.x];
  hL[threadIdx.x + 256] = h[b * HH + threadIdx.x + 256];
  __syncthreads();
  const int a = blockIdx.y * 256 + threadIdx.x;
  const float4* wr = (const float4*)(Wh + (size_t)a * HH);
  float acc = 0.f;
  #pragma unroll 4
  for (int j = 0; j < HH / 4; ++j) {
    float4 w = wr[j];
    acc += w.x * hL[4*j] + w.y * hL[4*j+1] + w.z * hL[4*j+2] + w.w * hL[4*j+3];
  }
  ph[b * AA + a] = acc;
}

// -------- fused scores: 128-row blocks, 8 waves, K-chunked dbuf, packed-B --------
// Wave (wr,wc): rows [wr*64,+64) x cols [wc*128,+128). A from LDS (verified path);
// B from packed web: each bfr load = contiguous 1 KB wave read (zero TA divergence).
__global__ __launch_bounds__(512, 4)
void scores_fullk(const float* __restrict__ enc, const unsigned short* __restrict__ web,
                  const float* __restrict__ ph, const float* __restrict__ vvec,
                  float* __restrict__ scores) {
  constexpr int RR  = 128;   // rows per block
  constexpr int CK  = 128;   // k-chunk (ushorts)
  constexpr int LDK = 136;   // padded chunk row stride (ushorts)

  __shared__ unsigned short As[2][RR * LDK];  // 69,632 B
  __shared__ float sred[4][RR];               // 2 KB

  const int tid  = threadIdx.x;
  const int lane = tid & 63;
  const int wid  = tid >> 6;      // 0..7
  const int wr   = wid >> 2;      // 0..1  row-group
  const int wc   = wid & 3;       // 0..3  col-group
  const int c    = lane & 15;
  const int quad = lane >> 4;

  const int r0 = blockIdx.x * RR;
  const int b  = r0 >> 11;        // 128 | 2048, tiles never cross batch

  // staging: thread covers rows {srow, srow+32, srow+64, srow+96}, 8 floats each
  const int srow = (tid * 8) >> 7;
  const int scol = (tid * 8) & 127;
  const float* encBase = enc + (size_t)r0 * DD;

  float4 lo[4], hi[4];

  auto LOADREGS = [&](int kc) {
    #pragma unroll
    for (int s = 0; s < 4; ++s) {
      const float* p = encBase + (size_t)(srow + s * 32) * DD + kc * CK + scol;
      lo[s] = *(const float4*)p;
      hi[s] = *(const float4*)(p + 4);
    }
  };
  auto WRITE = [&](int buf) {
    #pragma unroll
    for (int s = 0; s < 4; ++s)
      *(bf16x8*)&As[buf][(srow + s * 32) * LDK + scol] = pack8(lo[s], hi[s]);
  };

  // packed-B base for this wave's col-groups jc = wc*8 + j; per (j,kg) tile,
  // lane reads 16 B at tile*1024 + lane*16
  const unsigned short* bTile = web + (size_t)(wc * 8) * 16 * 512 + (lane << 3);

  float pp[8], vv[8];
  #pragma unroll
  for (int j = 0; j < 8; ++j) {
    const int col = wc * 128 + j * 16 + c;
    pp[j] = ph[b * AA + col];
    vv[j] = vvec[col];
  }

  f32x4 acc[4][8];
  #pragma unroll
  for (int i = 0; i < 4; ++i)
    #pragma unroll
    for (int j = 0; j < 8; ++j)
      acc[i][j] = (f32x4){0.f, 0.f, 0.f, 0.f};

  // prologue: stage chunk 0
  LOADREGS(0);
  WRITE(0);
  __syncthreads();

  #pragma unroll
  for (int kc = 0; kc < 4; ++kc) {
    const int cur = kc & 1;
    if (kc < 3) LOADREGS(kc + 1);              // issue next chunk's loads early

    const unsigned short* aB = &As[cur][(wr * 64 + c) * LDK + quad * 8];
    const int kg0 = kc * (CK / 32);            // k-group base this chunk
    #pragma unroll
    for (int k0 = 0; k0 < CK; k0 += 32) {
      const int kg = kg0 + (k0 >> 5);
      bf16x8 bfr[8];
      #pragma unroll
      for (int j = 0; j < 8; ++j)
        bfr[j] = *(const bf16x8*)(bTile + ((size_t)(j * 16 + kg) << 9));
      bf16x8 af[4];
      #pragma unroll
      for (int i = 0; i < 4; ++i)
        af[i] = *(const bf16x8*)(aB + i * 16 * LDK + k0);
      #pragma unroll
      for (int i = 0; i < 4; ++i)
        #pragma unroll
        for (int j = 0; j < 8; ++j)
          acc[i][j] = __builtin_amdgcn_mfma_f32_16x16x32_bf16(af[i], bfr[j], acc[i][j], 0, 0, 0);
    }

    if (kc < 3) WRITE(cur ^ 1);                // pack + ds_write after compute
    __syncthreads();
  }

  // epilogue: per-row partial = sum_cols v*tanh(acc+ph); C/D: row=quad*4+r, col=c
  #pragma unroll
  for (int i = 0; i < 4; ++i) {
    #pragma unroll
    for (int r = 0; r < 4; ++r) {
      float p = 0.f;
      #pragma unroll
      for (int j = 0; j < 8; ++j)
        p += vv[j] * fast_tanh(acc[i][j][r] + pp[j]);
      p += __shfl_xor(p, 1, 64);
      p += __shfl_xor(p, 2, 64);
      p += __shfl_xor(p, 4, 64);
      p += __shfl_xor(p, 8, 64);
      if (c == 0) sred[wc][wr * 64 + i * 16 + quad * 4 + r] = p;
    }
  }
  __syncthreads();
  if (tid < RR)
    scores[r0 + tid] = sred[0][tid] + sred[1][tid] + sred[2][tid] + sred[3][tid];
}

// -------- masked softmax over N per batch; alpha to d_out --------
__global__ __launch_bounds__(256)
void softmax_kernel(const float* __restrict__ scores, const int* __restrict__ mask,
                    float* __restrict__ alpha) {
  const int b = blockIdx.x, tid = threadIdx.x;
  const int base = b * NN;
  float vals[8];
  float mx = -3.4e38f;
  #pragma unroll
  for (int i = 0; i < 8; ++i) {
    int n = tid + 256 * i;
    float s = scores[base + n];
    if (mask[base + n] == 0) s = NEG_INF;
    vals[i] = s;
    mx = fmaxf(mx, s);
  }
  #pragma unroll
  for (int o = 32; o; o >>= 1) mx = fmaxf(mx, __shfl_xor(mx, o, 64));
  __shared__ float w4[4];
  if ((tid & 63) == 0) w4[tid >> 6] = mx;
  __syncthreads();
  mx = fmaxf(fmaxf(w4[0], w4[1]), fmaxf(w4[2], w4[3]));
  float sum = 0.f;
  #pragma unroll
  for (int i = 0; i < 8; ++i) { vals[i] = __expf(vals[i] - mx); sum += vals[i]; }
  #pragma unroll
  for (int o = 32; o; o >>= 1) sum += __shfl_xor(sum, o, 64);
  __shared__ float s4[4];
  if ((tid & 63) == 0) s4[tid >> 6] = sum;
  __syncthreads();
  sum = s4[0] + s4[1] + s4[2] + s4[3];
  float inv = 1.f / sum;
  #pragma unroll
  for (int i = 0; i < 8; ++i) alpha[base + tid + 256 * i] = vals[i] * inv;
}

// -------- context partials: 2048 blocks (64-row chunks), 4 accumulators --------
__global__ __launch_bounds__(128)
void context_part(const float* __restrict__ enc, const float* __restrict__ alpha,
                  float* __restrict__ cpart) {
  const int b  = blockIdx.x;
  const int nc = blockIdx.y;     // 32 chunks of 64 n
  const int t  = threadIdx.x;
  __shared__ float aL[64];
  if (t < 64) aL[t] = alpha[b * NN + nc * 64 + t];
  __syncthreads();
  const float* ep = enc + ((size_t)b * NN + nc * 64) * DD + t * 4;
  float4 a0 = {0.f, 0.f, 0.f, 0.f}, a1 = {0.f, 0.f, 0.f, 0.f};
  float4 a2 = {0.f, 0.f, 0.f, 0.f}, a3 = {0.f, 0.f, 0.f, 0.f};
  #pragma unroll 4
  for (int n = 0; n < 64; n += 4) {
    float4 e0 = *(const float4*)(ep + (size_t)n * DD);
    float4 e1 = *(const float4*)(ep + (size_t)(n + 1) * DD);
    float4 e2 = *(const float4*)(ep + (size_t)(n + 2) * DD);
    float4 e3 = *(const float4*)(ep + (size_t)(n + 3) * DD);
    float s0 = aL[n], s1 = aL[n + 1], s2 = aL[n + 2], s3 = aL[n + 3];
    a0.x += s0 * e0.x; a0.y += s0 * e0.y; a0.z += s0 * e0.z; a0.w += s0 * e0.w;
    a1.x += s1 * e1.x; a1.y += s1 * e1.y; a1.z += s1 * e1.z; a1.w += s1 * e1.w;
    a2.x += s2 * e2.x; a2.y += s2 * e2.y; a2.z += s2 * e2.z; a2.w += s2 * e2.w;
    a3.x += s3 * e3.x; a3.y += s3 * e3.y; a3.z += s3 * e3.z; a3.w += s3 * e3.w;
  }
  a0.x += a1.x + a2.x + a3.x;
  a0.y += a1.y + a2.y + a3.y;
  a0.z += a1.z + a2.z + a3.z;
  a0.w += a1.w + a2.w + a3.w;
  *(float4*)(cpart + ((size_t)(b * 32 + nc)) * DD + t * 4) = a0;
}

__global__ __launch_bounds__(256)
void context_reduce(const float* __restrict__ cpart, float* __restrict__ ctx) {
  const int i = blockIdx.x * 256 + threadIdx.x;   // 32768 = 64*512
  const int b = i >> 9, d = i & 511;
  float s = 0.f;
  #pragma unroll
  for (int nc = 0; nc < 32; ++nc) s += cpart[((size_t)(b * 32 + nc)) * DD + d];
  ctx[i] = s;
}

extern "C" void kernel_launch(void* const* d_in, const int* in_sizes, int n_in,
                              void* d_out, int out_size, void* d_ws, size_t ws_size,
                              hipStream_t stream) {
  const float* h    = (const float*)d_in[0];
  const float* enc  = (const float*)d_in[1];
  const int*   mask = (const int*)d_in[2];
  const float* Wh   = (const float*)d_in[3];
  const float* We   = (const float*)d_in[4];
  const float* v    = (const float*)d_in[5];

  float* out   = (float*)d_out;
  float* ctx   = out;                 // (B, D)
  float* alpha = out + BB * DD;       // (B, N)

  char* w = (char*)d_ws;
  unsigned short* web = (unsigned short*)w;                 // 512 KB (packed tiles)
  float* ph     = (float*)(w + (size_t)AA * DD * 2);        // 128 KB
  float* scores = ph + BB * AA;                             // 512 KB
  float* cpart  = scores + BB * NN;                         // 4 MB

  we_cast_kernel<<<(AA * DD / 8) / 256, 256, 0, stream>>>(We, web);
  proj_h_kernel<<<dim3(BB, 2), 256, 0, stream>>>(h, Wh, ph);
  scores_fullk<<<(BB * NN) / 128, 512, 0, stream>>>(enc, web, ph, v, scores);
  softmax_kernel<<<BB, 256, 0, stream>>>(scores, mask, alpha);
  context_part<<<dim3(BB, 32), 128, 0, stream>>>(enc, alpha, cpart);
  context_reduce<<<(BB * DD) / 256, 256, 0, stream>>>(cpart, ctx);
  (void)in_sizes; (void)n_in; (void)out_size; (void)ws_size;
}

// Round 6
// 490.765 us; speedup vs baseline: 2.6737x; 2.6737x over previous
//
#include <hip/hip_runtime.h>
#include <hip/hip_bf16.h>
#include <cstdint>
#include <cstddef>

#define NEG_INF (-1.0e9f)

typedef __attribute__((ext_vector_type(8))) short bf16x8;
typedef __attribute__((ext_vector_type(4))) float f32x4;

constexpr int BB = 64;     // batch
constexpr int NN = 2048;   // seq len
constexpr int HH = 512;    // h dim
constexpr int DD = 512;    // enc dim (GEMM K)
constexpr int AA = 512;    // attention dim (GEMM N)

__device__ __forceinline__ float fast_rcp(float x) {
#if __has_builtin(__builtin_amdgcn_rcpf)
  return __builtin_amdgcn_rcpf(x);
#else
  return 1.f / x;
#endif
}

__device__ __forceinline__ float fast_tanh(float x) {
  float e = __expf(2.f * fabsf(x));
  float t = 1.f - 2.f * fast_rcp(e + 1.f);
  return copysignf(t, x);
}

// 8 fp32 -> bf16x8 via packed HW cvt
__device__ __forceinline__ bf16x8 pack8(const float4& lo, const float4& hi) {
  __hip_bfloat162 a = __float22bfloat162_rn(float2{lo.x, lo.y});
  __hip_bfloat162 b = __float22bfloat162_rn(float2{lo.z, lo.w});
  __hip_bfloat162 c = __float22bfloat162_rn(float2{hi.x, hi.y});
  __hip_bfloat162 d = __float22bfloat162_rn(float2{hi.z, hi.w});
  union { unsigned int w[4]; bf16x8 v; } u;
  __builtin_memcpy(&u.w[0], &a, 4);
  __builtin_memcpy(&u.w[1], &b, 4);
  __builtin_memcpy(&u.w[2], &c, 4);
  __builtin_memcpy(&u.w[3], &d, 4);
  return u.v;
}

// -------- We -> bf16, packed into MFMA B-fragment tiles --------
// Tile (jc,kg) = cols [jc*16,+16) x k [kg*32,+32), stored as 512 ushorts at
// web[(jc*16+kg)*512], element order = lane-major: lane l holds
// We[jc*16 + (l&15)][kg*32 + (l>>4)*8 + e], e=0..7, at tile_off + l*8.
// A B-fragment load is then one fully-coalesced 1 KB wave read.
__global__ __launch_bounds__(256)
void we_cast_kernel(const float* __restrict__ We, unsigned short* __restrict__ web) {
  const int gid  = blockIdx.x * 256 + threadIdx.x;   // 32768 total
  const int l    = gid & 63;
  const int tile = gid >> 6;        // 0..511
  const int jc   = tile >> 4;       // col-group 0..31
  const int kg   = tile & 15;       // k-group  0..15
  const float* src = We + (size_t)(jc * 16 + (l & 15)) * DD + kg * 32 + (l >> 4) * 8;
  float4 s0 = *(const float4*)src;
  float4 s1 = *(const float4*)(src + 4);
  *(bf16x8*)(web + (size_t)tile * 512 + l * 8) = pack8(s0, s1);
}

// -------- proj_h --------
__global__ __launch_bounds__(256)
void proj_h_kernel(const float* __restrict__ h, const float* __restrict__ Wh,
                   float* __restrict__ ph) {
  __shared__ float hL[HH];
  const int b = blockIdx.x;
  hL[threadIdx.x]       = h[b * HH + threadIdx.x];
  hL[threadIdx.x + 256] = h[b * HH + threadIdx.x + 256];
  __syncthreads();
  const int a = blockIdx.y * 256 + threadIdx.x;
  const float4* wr = (const float4*)(Wh + (size_t)a * HH);
  float acc = 0.f;
  #pragma unroll 4
  for (int j = 0; j < HH / 4; ++j) {
    float4 w = wr[j];
    acc += w.x * hL[4*j] + w.y * hL[4*j+1] + w.z * hL[4*j+2] + w.w * hL[4*j+3];
  }
  ph[b * AA + a] = acc;
}

// -------- fused scores: 128-row blocks, 8 waves, K-chunked dbuf, packed-B --------
// Wave (wr,wc): rows [wr*64,+64) x cols [wc*128,+128). A from LDS (verified path);
// B from packed web: each bfr load = contiguous 1 KB wave read (zero TA divergence).
// launch_bounds (512,2): VERIFIED config — 128 arch VGPR + 128 acc, no spill.
// (512,4) forced a 64-VGPR cap -> full accumulator spill, 4.3x regression. Do not tighten.
__global__ __launch_bounds__(512, 2)
void scores_fullk(const float* __restrict__ enc, const unsigned short* __restrict__ web,
                  const float* __restrict__ ph, const float* __restrict__ vvec,
                  float* __restrict__ scores) {
  constexpr int RR  = 128;   // rows per block
  constexpr int CK  = 128;   // k-chunk (ushorts)
  constexpr int LDK = 136;   // padded chunk row stride (ushorts)

  __shared__ unsigned short As[2][RR * LDK];  // 69,632 B
  __shared__ float sred[4][RR];               // 2 KB

  const int tid  = threadIdx.x;
  const int lane = tid & 63;
  const int wid  = tid >> 6;      // 0..7
  const int wr   = wid >> 2;      // 0..1  row-group
  const int wc   = wid & 3;       // 0..3  col-group
  const int c    = lane & 15;
  const int quad = lane >> 4;

  const int r0 = blockIdx.x * RR;
  const int b  = r0 >> 11;        // 128 | 2048, tiles never cross batch

  // staging: thread covers rows {srow, srow+32, srow+64, srow+96}, 8 floats each
  const int srow = (tid * 8) >> 7;
  const int scol = (tid * 8) & 127;
  const float* encBase = enc + (size_t)r0 * DD;

  float4 lo[4], hi[4];

  auto LOADREGS = [&](int kc) {
    #pragma unroll
    for (int s = 0; s < 4; ++s) {
      const float* p = encBase + (size_t)(srow + s * 32) * DD + kc * CK + scol;
      lo[s] = *(const float4*)p;
      hi[s] = *(const float4*)(p + 4);
    }
  };
  auto WRITE = [&](int buf) {
    #pragma unroll
    for (int s = 0; s < 4; ++s)
      *(bf16x8*)&As[buf][(srow + s * 32) * LDK + scol] = pack8(lo[s], hi[s]);
  };

  // packed-B base for this wave's col-groups jc = wc*8 + j; per (j,kg) tile,
  // lane reads 16 B at tile*1024 + lane*16
  const unsigned short* bTile = web + (size_t)(wc * 8) * 16 * 512 + (lane << 3);

  float pp[8], vv[8];
  #pragma unroll
  for (int j = 0; j < 8; ++j) {
    const int col = wc * 128 + j * 16 + c;
    pp[j] = ph[b * AA + col];
    vv[j] = vvec[col];
  }

  f32x4 acc[4][8];
  #pragma unroll
  for (int i = 0; i < 4; ++i)
    #pragma unroll
    for (int j = 0; j < 8; ++j)
      acc[i][j] = (f32x4){0.f, 0.f, 0.f, 0.f};

  // prologue: stage chunk 0
  LOADREGS(0);
  WRITE(0);
  __syncthreads();

  #pragma unroll
  for (int kc = 0; kc < 4; ++kc) {
    const int cur = kc & 1;
    if (kc < 3) LOADREGS(kc + 1);              // issue next chunk's loads early

    const unsigned short* aB = &As[cur][(wr * 64 + c) * LDK + quad * 8];
    const int kg0 = kc * (CK / 32);            // k-group base this chunk
    #pragma unroll
    for (int k0 = 0; k0 < CK; k0 += 32) {
      const int kg = kg0 + (k0 >> 5);
      bf16x8 bfr[8];
      #pragma unroll
      for (int j = 0; j < 8; ++j)
        bfr[j] = *(const bf16x8*)(bTile + ((size_t)(j * 16 + kg) << 9));
      bf16x8 af[4];
      #pragma unroll
      for (int i = 0; i < 4; ++i)
        af[i] = *(const bf16x8*)(aB + i * 16 * LDK + k0);
      #pragma unroll
      for (int i = 0; i < 4; ++i)
        #pragma unroll
        for (int j = 0; j < 8; ++j)
          acc[i][j] = __builtin_amdgcn_mfma_f32_16x16x32_bf16(af[i], bfr[j], acc[i][j], 0, 0, 0);
    }

    if (kc < 3) WRITE(cur ^ 1);                // pack + ds_write after compute
    __syncthreads();
  }

  // epilogue: per-row partial = sum_cols v*tanh(acc+ph); C/D: row=quad*4+r, col=c
  #pragma unroll
  for (int i = 0; i < 4; ++i) {
    #pragma unroll
    for (int r = 0; r < 4; ++r) {
      float p = 0.f;
      #pragma unroll
      for (int j = 0; j < 8; ++j)
        p += vv[j] * fast_tanh(acc[i][j][r] + pp[j]);
      p += __shfl_xor(p, 1, 64);
      p += __shfl_xor(p, 2, 64);
      p += __shfl_xor(p, 4, 64);
      p += __shfl_xor(p, 8, 64);
      if (c == 0) sred[wc][wr * 64 + i * 16 + quad * 4 + r] = p;
    }
  }
  __syncthreads();
  if (tid < RR)
    scores[r0 + tid] = sred[0][tid] + sred[1][tid] + sred[2][tid] + sred[3][tid];
}

// -------- masked softmax over N per batch; alpha to d_out --------
__global__ __launch_bounds__(256)
void softmax_kernel(const float* __restrict__ scores, const int* __restrict__ mask,
                    float* __restrict__ alpha) {
  const int b = blockIdx.x, tid = threadIdx.x;
  const int base = b * NN;
  float vals[8];
  float mx = -3.4e38f;
  #pragma unroll
  for (int i = 0; i < 8; ++i) {
    int n = tid + 256 * i;
    float s = scores[base + n];
    if (mask[base + n] == 0) s = NEG_INF;
    vals[i] = s;
    mx = fmaxf(mx, s);
  }
  #pragma unroll
  for (int o = 32; o; o >>= 1) mx = fmaxf(mx, __shfl_xor(mx, o, 64));
  __shared__ float w4[4];
  if ((tid & 63) == 0) w4[tid >> 6] = mx;
  __syncthreads();
  mx = fmaxf(fmaxf(w4[0], w4[1]), fmaxf(w4[2], w4[3]));
  float sum = 0.f;
  #pragma unroll
  for (int i = 0; i < 8; ++i) { vals[i] = __expf(vals[i] - mx); sum += vals[i]; }
  #pragma unroll
  for (int o = 32; o; o >>= 1) sum += __shfl_xor(sum, o, 64);
  __shared__ float s4[4];
  if ((tid & 63) == 0) s4[tid >> 6] = sum;
  __syncthreads();
  sum = s4[0] + s4[1] + s4[2] + s4[3];
  float inv = 1.f / sum;
  #pragma unroll
  for (int i = 0; i < 8; ++i) alpha[base + tid + 256 * i] = vals[i] * inv;
}

// -------- context partials: 2048 blocks (64-row chunks), 4 accumulators --------
__global__ __launch_bounds__(128)
void context_part(const float* __restrict__ enc, const float* __restrict__ alpha,
                  float* __restrict__ cpart) {
  const int b  = blockIdx.x;
  const int nc = blockIdx.y;     // 32 chunks of 64 n
  const int t  = threadIdx.x;
  __shared__ float aL[64];
  if (t < 64) aL[t] = alpha[b * NN + nc * 64 + t];
  __syncthreads();
  const float* ep = enc + ((size_t)b * NN + nc * 64) * DD + t * 4;
  float4 a0 = {0.f, 0.f, 0.f, 0.f}, a1 = {0.f, 0.f, 0.f, 0.f};
  float4 a2 = {0.f, 0.f, 0.f, 0.f}, a3 = {0.f, 0.f, 0.f, 0.f};
  #pragma unroll 4
  for (int n = 0; n < 64; n += 4) {
    float4 e0 = *(const float4*)(ep + (size_t)n * DD);
    float4 e1 = *(const float4*)(ep + (size_t)(n + 1) * DD);
    float4 e2 = *(const float4*)(ep + (size_t)(n + 2) * DD);
    float4 e3 = *(const float4*)(ep + (size_t)(n + 3) * DD);
    float s0 = aL[n], s1 = aL[n + 1], s2 = aL[n + 2], s3 = aL[n + 3];
    a0.x += s0 * e0.x; a0.y += s0 * e0.y; a0.z += s0 * e0.z; a0.w += s0 * e0.w;
    a1.x += s1 * e1.x; a1.y += s1 * e1.y; a1.z += s1 * e1.z; a1.w += s1 * e1.w;
    a2.x += s2 * e2.x; a2.y += s2 * e2.y; a2.z += s2 * e2.z; a2.w += s2 * e2.w;
    a3.x += s3 * e3.x; a3.y += s3 * e3.y; a3.z += s3 * e3.z; a3.w += s3 * e3.w;
  }
  a0.x += a1.x + a2.x + a3.x;
  a0.y += a1.y + a2.y + a3.y;
  a0.z += a1.z + a2.z + a3.z;
  a0.w += a1.w + a2.w + a3.w;
  *(float4*)(cpart + ((size_t)(b * 32 + nc)) * DD + t * 4) = a0;
}

__global__ __launch_bounds__(256)
void context_reduce(const float* __restrict__ cpart, float* __restrict__ ctx) {
  const int i = blockIdx.x * 256 + threadIdx.x;   // 32768 = 64*512
  const int b = i >> 9, d = i & 511;
  float s = 0.f;
  #pragma unroll
  for (int nc = 0; nc < 32; ++nc) s += cpart[((size_t)(b * 32 + nc)) * DD + d];
  ctx[i] = s;
}

extern "C" void kernel_launch(void* const* d_in, const int* in_sizes, int n_in,
                              void* d_out, int out_size, void* d_ws, size_t ws_size,
                              hipStream_t stream) {
  const float* h    = (const float*)d_in[0];
  const float* enc  = (const float*)d_in[1];
  const int*   mask = (const int*)d_in[2];
  const float* Wh   = (const float*)d_in[3];
  const float* We   = (const float*)d_in[4];
  const float* v    = (const float*)d_in[5];

  float* out   = (float*)d_out;
  float* ctx   = out;                 // (B, D)
  float* alpha = out + BB * DD;       // (B, N)

  char* w = (char*)d_ws;
  unsigned short* web = (unsigned short*)w;                 // 512 KB (packed tiles)
  float* ph     = (float*)(w + (size_t)AA * DD * 2);        // 128 KB
  float* scores = ph + BB * AA;                             // 512 KB
  float* cpart  = scores + BB * NN;                         // 4 MB

  we_cast_kernel<<<(AA * DD / 8) / 256, 256, 0, stream>>>(We, web);
  proj_h_kernel<<<dim3(BB, 2), 256, 0, stream>>>(h, Wh, ph);
  scores_fullk<<<(BB * NN) / 128, 512, 0, stream>>>(enc, web, ph, v, scores);
  softmax_kernel<<<BB, 256, 0, stream>>>(scores, mask, alpha);
  context_part<<<dim3(BB, 32), 128, 0, stream>>>(enc, alpha, cpart);
  context_reduce<<<(BB * DD) / 256, 256, 0, stream>>>(cpart, ctx);
  (void)in_sizes; (void)n_in; (void)out_size; (void)ws_size;
}

// Round 8
// 468.940 us; speedup vs baseline: 2.7981x; 1.0465x over previous
//
#include <hip/hip_runtime.h>
#include <hip/hip_bf16.h>
#include <cstdint>
#include <cstddef>

#define NEG_INF (-1.0e9f)

typedef __attribute__((ext_vector_type(8))) short bf16x8;
typedef __attribute__((ext_vector_type(4))) float f32x4;

constexpr int BB = 64;     // batch
constexpr int NN = 2048;   // seq len
constexpr int HH = 512;    // h dim
constexpr int DD = 512;    // enc dim (GEMM K)
constexpr int AA = 512;    // attention dim (GEMM N)

__device__ __forceinline__ float fast_rcp(float x) {
#if __has_builtin(__builtin_amdgcn_rcpf)
  return __builtin_amdgcn_rcpf(x);
#else
  return 1.f / x;
#endif
}

__device__ __forceinline__ float fast_tanh(float x) {
  float e = __expf(2.f * fabsf(x));
  float t = 1.f - 2.f * fast_rcp(e + 1.f);
  return copysignf(t, x);
}

__device__ __forceinline__ float bf2f(unsigned short u) {
  return __uint_as_float(((unsigned int)u) << 16);
}

// 8 fp32 -> bf16x8 via packed HW cvt
__device__ __forceinline__ bf16x8 pack8(const float4& lo, const float4& hi) {
  __hip_bfloat162 a = __float22bfloat162_rn(float2{lo.x, lo.y});
  __hip_bfloat162 b = __float22bfloat162_rn(float2{lo.z, lo.w});
  __hip_bfloat162 c = __float22bfloat162_rn(float2{hi.x, hi.y});
  __hip_bfloat162 d = __float22bfloat162_rn(float2{hi.z, hi.w});
  union { unsigned int w[4]; bf16x8 v; } u;
  __builtin_memcpy(&u.w[0], &a, 4);
  __builtin_memcpy(&u.w[1], &b, 4);
  __builtin_memcpy(&u.w[2], &c, 4);
  __builtin_memcpy(&u.w[3], &d, 4);
  return u.v;
}

// -------- We -> bf16, packed into MFMA B-fragment tiles --------
// Tile (jc,kg) = cols [jc*16,+16) x k [kg*32,+32), 512 ushorts at web[(jc*16+kg)*512],
// lane-major so a B-fragment load is one fully-coalesced 1 KB wave read.
__global__ __launch_bounds__(256)
void we_cast_kernel(const float* __restrict__ We, unsigned short* __restrict__ web) {
  const int gid  = blockIdx.x * 256 + threadIdx.x;   // 32768 total
  const int l    = gid & 63;
  const int tile = gid >> 6;        // 0..511
  const int jc   = tile >> 4;       // col-group 0..31
  const int kg   = tile & 15;       // k-group  0..15
  const float* src = We + (size_t)(jc * 16 + (l & 15)) * DD + kg * 32 + (l >> 4) * 8;
  float4 s0 = *(const float4*)src;
  float4 s1 = *(const float4*)(src + 4);
  *(bf16x8*)(web + (size_t)tile * 512 + l * 8) = pack8(s0, s1);
}

// -------- proj_h --------
__global__ __launch_bounds__(256)
void proj_h_kernel(const float* __restrict__ h, const float* __restrict__ Wh,
                   float* __restrict__ ph) {
  __shared__ float hL[HH];
  const int b = blockIdx.x;
  hL[threadIdx.x]       = h[b * HH + threadIdx.x];
  hL[threadIdx.x + 256] = h[b * HH + threadIdx.x + 256];
  __syncthreads();
  const int a = blockIdx.y * 256 + threadIdx.x;
  const float4* wr = (const float4*)(Wh + (size_t)a * HH);
  float acc = 0.f;
  #pragma unroll 4
  for (int j = 0; j < HH / 4; ++j) {
    float4 w = wr[j];
    acc += w.x * hL[4*j] + w.y * hL[4*j+1] + w.z * hL[4*j+2] + w.w * hL[4*j+3];
  }
  ph[b * AA + a] = acc;
}

// -------- fused scores + partial context --------
// 128-row blocks, 8 waves, K-chunked staging into ONE full-K LDS tile (133 KB).
// GEMM/MFMA loop identical to the verified packed-B kernel. After scores, the
// epilogue does block-local online softmax (m, l, w[r]) and accumulates the
// partial context from the LDS bf16 tile -> zero extra HBM for context.
// launch_bounds (512,2): VERIFIED — 128 arch VGPR + 128 acc, no spill.
// (512,4) forced a 64-VGPR cap -> full accumulator spill, 4.3x regression. Do not tighten.
__global__ __launch_bounds__(512, 2)
void scores_ctx_fused(const float* __restrict__ enc, const unsigned short* __restrict__ web,
                      const float* __restrict__ ph, const float* __restrict__ vvec,
                      const int* __restrict__ mask,
                      float* __restrict__ scores, float* __restrict__ cpart,
                      float* __restrict__ ml) {
  constexpr int RR  = 128;   // rows per block
  constexpr int CK  = 128;   // k-chunk (floats staged per pass)
  constexpr int LDA = 520;   // full-K padded row stride (ushorts)

  __shared__ unsigned short As[RR * LDA];     // 133,120 B — full 128x512 bf16 tile
  __shared__ float sred[4][RR];               // 2 KB
  __shared__ float sfin[RR];                  // masked scores
  __shared__ float wgt[RR];                   // softmax weights
  __shared__ float mlred[2];                  // block m, l

  const int tid  = threadIdx.x;
  const int lane = tid & 63;
  const int wid  = tid >> 6;      // 0..7
  const int wr   = wid >> 2;      // 0..1  row-group
  const int wc   = wid & 3;       // 0..3  col-group
  const int c    = lane & 15;
  const int quad = lane >> 4;

  const int r0 = blockIdx.x * RR;
  const int b  = r0 >> 11;        // 128 | 2048, tiles never cross batch
  const int blk = blockIdx.x & 15;  // block-within-batch (2048/128 = 16)

  // staging: thread covers rows {srow, srow+32, srow+64, srow+96}, 8 floats each
  const int srow = (tid * 8) >> 7;
  const int scol = (tid * 8) & 127;
  const float* encBase = enc + (size_t)r0 * DD;

  float4 lo[4], hi[4];

  auto LOADREGS = [&](int kc) {
    #pragma unroll
    for (int s = 0; s < 4; ++s) {
      const float* p = encBase + (size_t)(srow + s * 32) * DD + kc * CK + scol;
      lo[s] = *(const float4*)p;
      hi[s] = *(const float4*)(p + 4);
    }
  };
  auto WRITE = [&](int kc) {
    #pragma unroll
    for (int s = 0; s < 4; ++s)
      *(bf16x8*)&As[(srow + s * 32) * LDA + kc * CK + scol] = pack8(lo[s], hi[s]);
  };

  // packed-B base: per (j,kg) tile, lane reads 16 B at tile*1024 + lane*16
  const unsigned short* bTile = web + (size_t)(wc * 8) * 16 * 512 + (lane << 3);

  float pp[8], vv[8];
  #pragma unroll
  for (int j = 0; j < 8; ++j) {
    const int col = wc * 128 + j * 16 + c;
    pp[j] = ph[b * AA + col];
    vv[j] = vvec[col];
  }

  f32x4 acc[4][8];
  #pragma unroll
  for (int i = 0; i < 4; ++i)
    #pragma unroll
    for (int j = 0; j < 8; ++j)
      acc[i][j] = (f32x4){0.f, 0.f, 0.f, 0.f};

  // prologue: stage chunk 0
  LOADREGS(0);
  WRITE(0);
  __syncthreads();

  #pragma unroll
  for (int kc = 0; kc < 4; ++kc) {
    if (kc < 3) LOADREGS(kc + 1);              // issue next chunk's loads early

    const unsigned short* aB = &As[(wr * 64 + c) * LDA + kc * CK + quad * 8];
    const int kg0 = kc * (CK / 32);            // k-group base this chunk
    #pragma unroll
    for (int k0 = 0; k0 < CK; k0 += 32) {
      const int kg = kg0 + (k0 >> 5);
      bf16x8 bfr[8];
      #pragma unroll
      for (int j = 0; j < 8; ++j)
        bfr[j] = *(const bf16x8*)(bTile + ((size_t)(j * 16 + kg) << 9));
      bf16x8 af[4];
      #pragma unroll
      for (int i = 0; i < 4; ++i)
        af[i] = *(const bf16x8*)(aB + i * 16 * LDA + k0);
      #pragma unroll
      for (int i = 0; i < 4; ++i)
        #pragma unroll
        for (int j = 0; j < 8; ++j)
          acc[i][j] = __builtin_amdgcn_mfma_f32_16x16x32_bf16(af[i], bfr[j], acc[i][j], 0, 0, 0);
    }

    if (kc < 3) WRITE(kc + 1);                 // pack + ds_write after compute
    __syncthreads();                           // chunk kc+1 visible; no WAR (new cols)
  }

  // scores epilogue: per-row partial = sum_cols v*tanh(acc+ph); C/D: row=quad*4+r, col=c
  #pragma unroll
  for (int i = 0; i < 4; ++i) {
    #pragma unroll
    for (int r = 0; r < 4; ++r) {
      float p = 0.f;
      #pragma unroll
      for (int j = 0; j < 8; ++j)
        p += vv[j] * fast_tanh(acc[i][j][r] + pp[j]);
      p += __shfl_xor(p, 1, 64);
      p += __shfl_xor(p, 2, 64);
      p += __shfl_xor(p, 4, 64);
      p += __shfl_xor(p, 8, 64);
      if (c == 0) sred[wc][wr * 64 + i * 16 + quad * 4 + r] = p;
    }
  }
  __syncthreads();

  // finalize scores, apply mask into sfin
  if (tid < RR) {
    float s = sred[0][tid] + sred[1][tid] + sred[2][tid] + sred[3][tid];
    scores[r0 + tid] = s;
    sfin[tid] = (mask[r0 + tid] == 0) ? NEG_INF : s;
  }
  __syncthreads();

  // block max m (one wave)
  if (tid < 64) {
    float v = fmaxf(sfin[tid], sfin[tid + 64]);
    #pragma unroll
    for (int o = 32; o; o >>= 1) v = fmaxf(v, __shfl_xor(v, o, 64));
    if (tid == 0) mlred[0] = v;
  }
  __syncthreads();
  const float mblk = mlred[0];

  // weights + block sum l (one wave)
  if (tid < 64) {
    float w0 = __expf(sfin[tid] - mblk);
    float w1 = __expf(sfin[tid + 64] - mblk);
    wgt[tid] = w0; wgt[tid + 64] = w1;
    float v = w0 + w1;
    #pragma unroll
    for (int o = 32; o; o >>= 1) v += __shfl_xor(v, o, 64);
    if (tid == 0) mlred[1] = v;
  }
  __syncthreads();

  // partial context from the LDS bf16 tile: thread t owns column t
  {
    const unsigned short* colp = &As[tid];
    float a0 = 0.f, a1 = 0.f, a2 = 0.f, a3 = 0.f;
    #pragma unroll 4
    for (int r = 0; r < RR; r += 4) {
      a0 += wgt[r]     * bf2f(colp[(size_t)(r    ) * LDA]);
      a1 += wgt[r + 1] * bf2f(colp[(size_t)(r + 1) * LDA]);
      a2 += wgt[r + 2] * bf2f(colp[(size_t)(r + 2) * LDA]);
      a3 += wgt[r + 3] * bf2f(colp[(size_t)(r + 3) * LDA]);
    }
    cpart[((size_t)(b * 16 + blk)) * DD + tid] = (a0 + a1) + (a2 + a3);
  }
  if (tid == 0) {
    ml[(b * 16 + blk) * 2]     = mblk;
    ml[(b * 16 + blk) * 2 + 1] = mlred[1];
  }
}

// -------- masked softmax over N per batch; alpha to d_out (unchanged) --------
__global__ __launch_bounds__(256)
void softmax_kernel(const float* __restrict__ scores, const int* __restrict__ mask,
                    float* __restrict__ alpha) {
  const int b = blockIdx.x, tid = threadIdx.x;
  const int base = b * NN;
  float vals[8];
  float mx = -3.4e38f;
  #pragma unroll
  for (int i = 0; i < 8; ++i) {
    int n = tid + 256 * i;
    float s = scores[base + n];
    if (mask[base + n] == 0) s = NEG_INF;
    vals[i] = s;
    mx = fmaxf(mx, s);
  }
  #pragma unroll
  for (int o = 32; o; o >>= 1) mx = fmaxf(mx, __shfl_xor(mx, o, 64));
  __shared__ float w4[4];
  if ((tid & 63) == 0) w4[tid >> 6] = mx;
  __syncthreads();
  mx = fmaxf(fmaxf(w4[0], w4[1]), fmaxf(w4[2], w4[3]));
  float sum = 0.f;
  #pragma unroll
  for (int i = 0; i < 8; ++i) { vals[i] = __expf(vals[i] - mx); sum += vals[i]; }
  #pragma unroll
  for (int o = 32; o; o >>= 1) sum += __shfl_xor(sum, o, 64);
  __shared__ float s4[4];
  if ((tid & 63) == 0) s4[tid >> 6] = sum;
  __syncthreads();
  sum = s4[0] + s4[1] + s4[2] + s4[3];
  float inv = 1.f / sum;
  #pragma unroll
  for (int i = 0; i < 8; ++i) alpha[base + tid + 256 * i] = vals[i] * inv;
}

// -------- combine per-block (m, l, cpart) partials into context --------
// ctx_b = sum_i e^{m_i-M} c_i / sum_i l_i e^{m_i-M}  — exact online-softmax merge.
__global__ __launch_bounds__(512)
void context_combine(const float* __restrict__ cpart, const float* __restrict__ ml,
                     float* __restrict__ ctx) {
  const int b = blockIdx.x, t = threadIdx.x;
  __shared__ float mls[32];
  if (t < 32) mls[t] = ml[b * 32 + t];
  __syncthreads();
  float M = -3.4e38f;
  #pragma unroll
  for (int i = 0; i < 16; ++i) M = fmaxf(M, mls[2 * i]);
  float w[16];
  float L = 0.f;
  #pragma unroll
  for (int i = 0; i < 16; ++i) {
    w[i] = __expf(mls[2 * i] - M);
    L += mls[2 * i + 1] * w[i];
  }
  float acc = 0.f;
  #pragma unroll
  for (int i = 0; i < 16; ++i)
    acc += w[i] * cpart[((size_t)(b * 16 + i)) * DD + t];
  ctx[b * DD + t] = acc / L;
}

extern "C" void kernel_launch(void* const* d_in, const int* in_sizes, int n_in,
                              void* d_out, int out_size, void* d_ws, size_t ws_size,
                              hipStream_t stream) {
  const float* h    = (const float*)d_in[0];
  const float* enc  = (const float*)d_in[1];
  const int*   mask = (const int*)d_in[2];
  const float* Wh   = (const float*)d_in[3];
  const float* We   = (const float*)d_in[4];
  const float* v    = (const float*)d_in[5];

  float* out   = (float*)d_out;
  float* ctx   = out;                 // (B, D)
  float* alpha = out + BB * DD;       // (B, N)

  char* w = (char*)d_ws;
  unsigned short* web = (unsigned short*)w;                 // 512 KB (packed tiles)
  float* ph     = (float*)(w + (size_t)AA * DD * 2);        // 128 KB
  float* scores = ph + BB * AA;                             // 512 KB
  float* cpart  = scores + BB * NN;                         // 2 MB (64*16*512)
  float* ml     = cpart + BB * 16 * DD;                     // 8 KB (64*16*2)

  we_cast_kernel<<<(AA * DD / 8) / 256, 256, 0, stream>>>(We, web);
  proj_h_kernel<<<dim3(BB, 2), 256, 0, stream>>>(h, Wh, ph);
  scores_ctx_fused<<<(BB * NN) / 128, 512, 0, stream>>>(enc, web, ph, v, mask,
                                                        scores, cpart, ml);
  softmax_kernel<<<BB, 256, 0, stream>>>(scores, mask, alpha);
  context_combine<<<BB, 512, 0, stream>>>(cpart, ml, ctx);
  (void)in_sizes; (void)n_in; (void)out_size; (void)ws_size;
}

// Round 12
// 455.112 us; speedup vs baseline: 2.8831x; 1.0304x over previous
//
#include <hip/hip_runtime.h>
#include <hip/hip_bf16.h>
#include <cstdint>
#include <cstddef>

#define NEG_INF (-1.0e9f)

typedef __attribute__((ext_vector_type(8))) short bf16x8;
typedef __attribute__((ext_vector_type(4))) float f32x4;

constexpr int BB = 64;     // batch
constexpr int NN = 2048;   // seq len
constexpr int HH = 512;    // h dim
constexpr int DD = 512;    // enc dim (GEMM K)
constexpr int AA = 512;    // attention dim (GEMM N)

__device__ __forceinline__ float fast_rcp(float x) {
#if __has_builtin(__builtin_amdgcn_rcpf)
  return __builtin_amdgcn_rcpf(x);
#else
  return 1.f / x;
#endif
}

__device__ __forceinline__ float fast_tanh(float x) {
  float e = __expf(2.f * fabsf(x));
  float t = 1.f - 2.f * fast_rcp(e + 1.f);
  return copysignf(t, x);
}

__device__ __forceinline__ float bf2f(unsigned short u) {
  return __uint_as_float(((unsigned int)u) << 16);
}

// 8 fp32 -> bf16x8 via packed HW cvt
__device__ __forceinline__ bf16x8 pack8(const float4& lo, const float4& hi) {
  __hip_bfloat162 a = __float22bfloat162_rn(float2{lo.x, lo.y});
  __hip_bfloat162 b = __float22bfloat162_rn(float2{lo.z, lo.w});
  __hip_bfloat162 c = __float22bfloat162_rn(float2{hi.x, hi.y});
  __hip_bfloat162 d = __float22bfloat162_rn(float2{hi.z, hi.w});
  union { unsigned int w[4]; bf16x8 v; } u;
  __builtin_memcpy(&u.w[0], &a, 4);
  __builtin_memcpy(&u.w[1], &b, 4);
  __builtin_memcpy(&u.w[2], &c, 4);
  __builtin_memcpy(&u.w[3], &d, 4);
  return u.v;
}

// -------- We -> bf16, packed into MFMA B-fragment tiles --------
// Tile (jc,kg) = cols [jc*16,+16) x k [kg*32,+32), 512 ushorts at web[(jc*16+kg)*512],
// lane-major so a B-fragment load is one fully-coalesced 1 KB wave read.
__global__ __launch_bounds__(256)
void we_cast_kernel(const float* __restrict__ We, unsigned short* __restrict__ web) {
  const int gid  = blockIdx.x * 256 + threadIdx.x;   // 32768 total
  const int l    = gid & 63;
  const int tile = gid >> 6;        // 0..511
  const int jc   = tile >> 4;       // col-group 0..31
  const int kg   = tile & 15;       // k-group  0..15
  const float* src = We + (size_t)(jc * 16 + (l & 15)) * DD + kg * 32 + (l >> 4) * 8;
  float4 s0 = *(const float4*)src;
  float4 s1 = *(const float4*)(src + 4);
  *(bf16x8*)(web + (size_t)tile * 512 + l * 8) = pack8(s0, s1);
}

// -------- proj_h --------
__global__ __launch_bounds__(256)
void proj_h_kernel(const float* __restrict__ h, const float* __restrict__ Wh,
                   float* __restrict__ ph) {
  __shared__ float hL[HH];
  const int b = blockIdx.x;
  hL[threadIdx.x]       = h[b * HH + threadIdx.x];
  hL[threadIdx.x + 256] = h[b * HH + threadIdx.x + 256];
  __syncthreads();
  const int a = blockIdx.y * 256 + threadIdx.x;
  const float4* wr = (const float4*)(Wh + (size_t)a * HH);
  float acc = 0.f;
  #pragma unroll 4
  for (int j = 0; j < HH / 4; ++j) {
    float4 w = wr[j];
    acc += w.x * hL[4*j] + w.y * hL[4*j+1] + w.z * hL[4*j+2] + w.w * hL[4*j+3];
  }
  ph[b * AA + a] = acc;
}

// -------- fused scores + partial context, 64-row / 4-wave geometry --------
// 2 blocks/CU (66.5 KB LDS): co-resident blocks' phases decorrelate (staging/
// epilogue of one overlaps MFMA of the other). Wave wc: all 64 rows x cols
// [wc*128,+128). Packed-B (1 KB coalesced wave reads). Full-K LDS tile, chunked
// staging. Epilogue: block-local online softmax + context partial from LDS.
// launch_bounds (256,2): VERIFIED (R0 geometry) — 128 arch + 128 acc, no spill.
__global__ __launch_bounds__(256, 2)
void scores_ctx_fused(const float* __restrict__ enc, const unsigned short* __restrict__ web,
                      const float* __restrict__ ph, const float* __restrict__ vvec,
                      const int* __restrict__ mask,
                      float* __restrict__ scores, float* __restrict__ cpart,
                      float* __restrict__ ml) {
  constexpr int RR  = 64;    // rows per block
  constexpr int CK  = 128;   // k-chunk (floats staged per pass)
  constexpr int LDA = 520;   // full-K padded row stride (ushorts)

  __shared__ unsigned short As[RR * LDA];     // 66,560 B — full 64x512 bf16 tile
  __shared__ float sred[4][RR];               // 1 KB
  __shared__ float sfin[RR];                  // masked scores
  __shared__ float wgt[RR];                   // softmax weights
  __shared__ float mlred[2];                  // block m, l

  const int tid  = threadIdx.x;
  const int lane = tid & 63;
  const int wc   = tid >> 6;      // 0..3  col-group (wave id)
  const int c    = lane & 15;
  const int quad = lane >> 4;

  const int r0 = blockIdx.x * RR;
  const int b  = r0 >> 11;          // 64 | 2048, tiles never cross batch
  const int blk = blockIdx.x & 31;  // block-within-batch (2048/64 = 32)

  // staging: thread covers rows {srow, srow+16, srow+32, srow+48}, 8 floats each
  const int srow = (tid * 8) >> 7;  // 0..15
  const int scol = (tid * 8) & 127;
  const float* encBase = enc + (size_t)r0 * DD;

  float4 lo[4], hi[4];

  auto LOADREGS = [&](int kc) {
    #pragma unroll
    for (int s = 0; s < 4; ++s) {
      const float* p = encBase + (size_t)(srow + s * 16) * DD + kc * CK + scol;
      lo[s] = *(const float4*)p;
      hi[s] = *(const float4*)(p + 4);
    }
  };
  auto WRITE = [&](int kc) {
    #pragma unroll
    for (int s = 0; s < 4; ++s)
      *(bf16x8*)&As[(srow + s * 16) * LDA + kc * CK + scol] = pack8(lo[s], hi[s]);
  };

  // packed-B base: per (j,kg) tile, lane reads 16 B at tile*1024 + lane*16
  const unsigned short* bTile = web + (size_t)(wc * 8) * 16 * 512 + (lane << 3);

  float pp[8], vv[8];
  #pragma unroll
  for (int j = 0; j < 8; ++j) {
    const int col = wc * 128 + j * 16 + c;
    pp[j] = ph[b * AA + col];
    vv[j] = vvec[col];
  }

  f32x4 acc[4][8];
  #pragma unroll
  for (int i = 0; i < 4; ++i)
    #pragma unroll
    for (int j = 0; j < 8; ++j)
      acc[i][j] = (f32x4){0.f, 0.f, 0.f, 0.f};

  // prologue: stage chunk 0
  LOADREGS(0);
  WRITE(0);
  __syncthreads();

  #pragma unroll
  for (int kc = 0; kc < 4; ++kc) {
    if (kc < 3) LOADREGS(kc + 1);              // issue next chunk's loads early

    const unsigned short* aB = &As[c * LDA + kc * CK + quad * 8];
    const int kg0 = kc * (CK / 32);            // k-group base this chunk
    #pragma unroll
    for (int k0 = 0; k0 < CK; k0 += 32) {
      const int kg = kg0 + (k0 >> 5);
      bf16x8 bfr[8];
      #pragma unroll
      for (int j = 0; j < 8; ++j)
        bfr[j] = *(const bf16x8*)(bTile + ((size_t)(j * 16 + kg) << 9));
      bf16x8 af[4];
      #pragma unroll
      for (int i = 0; i < 4; ++i)
        af[i] = *(const bf16x8*)(aB + i * 16 * LDA + k0);
      #pragma unroll
      for (int i = 0; i < 4; ++i)
        #pragma unroll
        for (int j = 0; j < 8; ++j)
          acc[i][j] = __builtin_amdgcn_mfma_f32_16x16x32_bf16(af[i], bfr[j], acc[i][j], 0, 0, 0);
    }

    if (kc < 3) WRITE(kc + 1);                 // pack + ds_write after compute
    __syncthreads();                           // chunk kc+1 visible; no WAR (new cols)
  }

  // scores epilogue: per-row partial = sum_cols v*tanh(acc+ph); C/D: row=quad*4+r, col=c
  #pragma unroll
  for (int i = 0; i < 4; ++i) {
    #pragma unroll
    for (int r = 0; r < 4; ++r) {
      float p = 0.f;
      #pragma unroll
      for (int j = 0; j < 8; ++j)
        p += vv[j] * fast_tanh(acc[i][j][r] + pp[j]);
      p += __shfl_xor(p, 1, 64);
      p += __shfl_xor(p, 2, 64);
      p += __shfl_xor(p, 4, 64);
      p += __shfl_xor(p, 8, 64);
      if (c == 0) sred[wc][i * 16 + quad * 4 + r] = p;
    }
  }
  __syncthreads();

  // finalize scores, apply mask into sfin
  if (tid < RR) {
    float s = sred[0][tid] + sred[1][tid] + sred[2][tid] + sred[3][tid];
    scores[r0 + tid] = s;
    sfin[tid] = (mask[r0 + tid] == 0) ? NEG_INF : s;
  }
  __syncthreads();

  // block max m (one wave over 64 rows)
  if (tid < 64) {
    float v = sfin[tid];
    #pragma unroll
    for (int o = 32; o; o >>= 1) v = fmaxf(v, __shfl_xor(v, o, 64));
    if (tid == 0) mlred[0] = v;
  }
  __syncthreads();
  const float mblk = mlred[0];

  // weights + block sum l (one wave)
  if (tid < 64) {
    float w0 = __expf(sfin[tid] - mblk);
    wgt[tid] = w0;
    float v = w0;
    #pragma unroll
    for (int o = 32; o; o >>= 1) v += __shfl_xor(v, o, 64);
    if (tid == 0) mlred[1] = v;
  }
  __syncthreads();

  // partial context from the LDS bf16 tile: thread t owns columns t and t+256
  #pragma unroll
  for (int cc = 0; cc < 2; ++cc) {
    const int col = tid + cc * 256;
    const unsigned short* colp = &As[col];
    float a0 = 0.f, a1 = 0.f, a2 = 0.f, a3 = 0.f;
    #pragma unroll 4
    for (int r = 0; r < RR; r += 4) {
      a0 += wgt[r]     * bf2f(colp[(size_t)(r    ) * LDA]);
      a1 += wgt[r + 1] * bf2f(colp[(size_t)(r + 1) * LDA]);
      a2 += wgt[r + 2] * bf2f(colp[(size_t)(r + 2) * LDA]);
      a3 += wgt[r + 3] * bf2f(colp[(size_t)(r + 3) * LDA]);
    }
    cpart[((size_t)(b * 32 + blk)) * DD + col] = (a0 + a1) + (a2 + a3);
  }
  if (tid == 0) {
    ml[(b * 32 + blk) * 2]     = mblk;
    ml[(b * 32 + blk) * 2 + 1] = mlred[1];
  }
}

// -------- masked softmax over N per batch; alpha to d_out (unchanged) --------
__global__ __launch_bounds__(256)
void softmax_kernel(const float* __restrict__ scores, const int* __restrict__ mask,
                    float* __restrict__ alpha) {
  const int b = blockIdx.x, tid = threadIdx.x;
  const int base = b * NN;
  float vals[8];
  float mx = -3.4e38f;
  #pragma unroll
  for (int i = 0; i < 8; ++i) {
    int n = tid + 256 * i;
    float s = scores[base + n];
    if (mask[base + n] == 0) s = NEG_INF;
    vals[i] = s;
    mx = fmaxf(mx, s);
  }
  #pragma unroll
  for (int o = 32; o; o >>= 1) mx = fmaxf(mx, __shfl_xor(mx, o, 64));
  __shared__ float w4[4];
  if ((tid & 63) == 0) w4[tid >> 6] = mx;
  __syncthreads();
  mx = fmaxf(fmaxf(w4[0], w4[1]), fmaxf(w4[2], w4[3]));
  float sum = 0.f;
  #pragma unroll
  for (int i = 0; i < 8; ++i) { vals[i] = __expf(vals[i] - mx); sum += vals[i]; }
  #pragma unroll
  for (int o = 32; o; o >>= 1) sum += __shfl_xor(sum, o, 64);
  __shared__ float s4[4];
  if ((tid & 63) == 0) s4[tid >> 6] = sum;
  __syncthreads();
  sum = s4[0] + s4[1] + s4[2] + s4[3];
  float inv = 1.f / sum;
  #pragma unroll
  for (int i = 0; i < 8; ++i) alpha[base + tid + 256 * i] = vals[i] * inv;
}

// -------- combine per-block (m, l, cpart) partials into context --------
// ctx_b = sum_i e^{m_i-M} c_i / sum_i l_i e^{m_i-M}  — exact online-softmax merge.
__global__ __launch_bounds__(512)
void context_combine(const float* __restrict__ cpart, const float* __restrict__ ml,
                     float* __restrict__ ctx) {
  const int b = blockIdx.x, t = threadIdx.x;
  __shared__ float mls[64];
  if (t < 64) mls[t] = ml[b * 64 + t];
  __syncthreads();
  float M = -3.4e38f;
  #pragma unroll
  for (int i = 0; i < 32; ++i) M = fmaxf(M, mls[2 * i]);
  float L = 0.f;
  float acc = 0.f;
  #pragma unroll
  for (int i = 0; i < 32; ++i) {
    float w = __expf(mls[2 * i] - M);
    L += mls[2 * i + 1] * w;
    acc += w * cpart[((size_t)(b * 32 + i)) * DD + t];
  }
  ctx[b * DD + t] = acc / L;
}

extern "C" void kernel_launch(void* const* d_in, const int* in_sizes, int n_in,
                              void* d_out, int out_size, void* d_ws, size_t ws_size,
                              hipStream_t stream) {
  const float* h    = (const float*)d_in[0];
  const float* enc  = (const float*)d_in[1];
  const int*   mask = (const int*)d_in[2];
  const float* Wh   = (const float*)d_in[3];
  const float* We   = (const float*)d_in[4];
  const float* v    = (const float*)d_in[5];

  float* out   = (float*)d_out;
  float* ctx   = out;                 // (B, D)
  float* alpha = out + BB * DD;       // (B, N)

  char* w = (char*)d_ws;
  unsigned short* web = (unsigned short*)w;                 // 512 KB (packed tiles)
  float* ph     = (float*)(w + (size_t)AA * DD * 2);        // 128 KB
  float* scores = ph + BB * AA;                             // 512 KB
  float* cpart  = scores + BB * NN;                         // 4 MB (64*32*512)
  float* ml     = cpart + BB * 32 * DD;                     // 16 KB (64*32*2)

  we_cast_kernel<<<(AA * DD / 8) / 256, 256, 0, stream>>>(We, web);
  proj_h_kernel<<<dim3(BB, 2), 256, 0, stream>>>(h, Wh, ph);
  scores_ctx_fused<<<(BB * NN) / 64, 256, 0, stream>>>(enc, web, ph, v, mask,
                                                       scores, cpart, ml);
  softmax_kernel<<<BB, 256, 0, stream>>>(scores, mask, alpha);
  context_combine<<<BB, 512, 0, stream>>>(cpart, ml, ctx);
  (void)in_sizes; (void)n_in; (void)out_size; (void)ws_size;
}

// Round 17
// 449.821 us; speedup vs baseline: 2.9170x; 1.0118x over previous
//
#include <hip/hip_runtime.h>
#include <hip/hip_bf16.h>
#include <cstdint>
#include <cstddef>

#define NEG_INF (-1.0e9f)

typedef __attribute__((ext_vector_type(8))) short bf16x8;
typedef __attribute__((ext_vector_type(4))) float f32x4;

constexpr int BB = 64;     // batch
constexpr int NN = 2048;   // seq len
constexpr int HH = 512;    // h dim
constexpr int DD = 512;    // enc dim (GEMM K)
constexpr int AA = 512;    // attention dim (GEMM N)

__device__ __forceinline__ float fast_rcp(float x) {
#if __has_builtin(__builtin_amdgcn_rcpf)
  return __builtin_amdgcn_rcpf(x);
#else
  return 1.f / x;
#endif
}

__device__ __forceinline__ float fast_tanh(float x) {
  float e = __expf(2.f * fabsf(x));
  float t = 1.f - 2.f * fast_rcp(e + 1.f);
  return copysignf(t, x);
}

__device__ __forceinline__ float bf2f(unsigned short u) {
  return __uint_as_float(((unsigned int)u) << 16);
}

// 8 fp32 -> bf16x8 via packed HW cvt
__device__ __forceinline__ bf16x8 pack8(const float4& lo, const float4& hi) {
  __hip_bfloat162 a = __float22bfloat162_rn(float2{lo.x, lo.y});
  __hip_bfloat162 b = __float22bfloat162_rn(float2{lo.z, lo.w});
  __hip_bfloat162 c = __float22bfloat162_rn(float2{hi.x, hi.y});
  __hip_bfloat162 d = __float22bfloat162_rn(float2{hi.z, hi.w});
  union { unsigned int w[4]; bf16x8 v; } u;
  __builtin_memcpy(&u.w[0], &a, 4);
  __builtin_memcpy(&u.w[1], &b, 4);
  __builtin_memcpy(&u.w[2], &c, 4);
  __builtin_memcpy(&u.w[3], &d, 4);
  return u.v;
}

// -------- prep: we_cast (blocks 0..127) + proj_h (blocks 128..255) --------
// we_cast: We -> bf16 packed MFMA B-fragment tiles. Tile (jc,kg) = cols
// [jc*16,+16) x k [kg*32,+32), 512 ushorts at web[(jc*16+kg)*512], lane-major
// so a B-fragment load is one fully-coalesced 1 KB wave read.
// proj_h: ph[b][a] = dot(Wh[a], h[b]); original grid (64,2) flattened.
__global__ __launch_bounds__(256)
void prep_kernel(const float* __restrict__ We, unsigned short* __restrict__ web,
                 const float* __restrict__ h, const float* __restrict__ Wh,
                 float* __restrict__ ph) {
  __shared__ float hL[HH];
  if (blockIdx.x < 128) {
    const int gid  = blockIdx.x * 256 + threadIdx.x;   // 32768 total
    const int l    = gid & 63;
    const int tile = gid >> 6;        // 0..511
    const int jc   = tile >> 4;       // col-group 0..31
    const int kg   = tile & 15;       // k-group  0..15
    const float* src = We + (size_t)(jc * 16 + (l & 15)) * DD + kg * 32 + (l >> 4) * 8;
    float4 s0 = *(const float4*)src;
    float4 s1 = *(const float4*)(src + 4);
    *(bf16x8*)(web + (size_t)tile * 512 + l * 8) = pack8(s0, s1);
  } else {
    const int idx  = blockIdx.x - 128;   // 0..127
    const int b    = idx >> 1;           // 0..63
    const int half = idx & 1;            // 0..1
    hL[threadIdx.x]       = h[b * HH + threadIdx.x];
    hL[threadIdx.x + 256] = h[b * HH + threadIdx.x + 256];
    __syncthreads();
    const int a = half * 256 + threadIdx.x;
    const float4* wr = (const float4*)(Wh + (size_t)a * HH);
    float acc = 0.f;
    #pragma unroll 4
    for (int j = 0; j < HH / 4; ++j) {
      float4 w = wr[j];
      acc += w.x * hL[4*j] + w.y * hL[4*j+1] + w.z * hL[4*j+2] + w.w * hL[4*j+3];
    }
    ph[b * AA + a] = acc;
  }
}

// -------- fused scores + partial context, 64-row / 4-wave geometry --------
// 2 blocks/CU (66.5 KB LDS). Wave wc: all 64 rows x cols [wc*128,+128).
// Packed-B (1 KB coalesced wave reads). Full-K LDS tile, chunked staging.
// Epilogue: block-local online softmax + context partial from LDS.
// launch_bounds (256,2): VERIFIED — 128 arch + 128 acc = 256/wave, exactly the
// 2-waves/SIMD budget; no spill. NOTE: zero VGPR headroom -> compiler cannot
// software-pipeline bfr loads across kg steps (the 17% MfmaUtil latency bind).
// (512,4)-style tightening forced a 64-VGPR cap -> full spill, 4.3x regression. Do not tighten.
__global__ __launch_bounds__(256, 2)
void scores_ctx_fused(const float* __restrict__ enc, const unsigned short* __restrict__ web,
                      const float* __restrict__ ph, const float* __restrict__ vvec,
                      const int* __restrict__ mask,
                      float* __restrict__ scores, float* __restrict__ cpart,
                      float* __restrict__ ml) {
  constexpr int RR  = 64;    // rows per block
  constexpr int CK  = 128;   // k-chunk (floats staged per pass)
  constexpr int LDA = 520;   // full-K padded row stride (ushorts)

  __shared__ unsigned short As[RR * LDA];     // 66,560 B — full 64x512 bf16 tile
  __shared__ float sred[4][RR];               // 1 KB
  __shared__ float sfin[RR];                  // masked scores
  __shared__ float wgt[RR];                   // softmax weights
  __shared__ float mlred[2];                  // block m, l

  const int tid  = threadIdx.x;
  const int lane = tid & 63;
  const int wc   = tid >> 6;      // 0..3  col-group (wave id)
  const int c    = lane & 15;
  const int quad = lane >> 4;

  const int r0 = blockIdx.x * RR;
  const int b  = r0 >> 11;          // 64 | 2048, tiles never cross batch
  const int blk = blockIdx.x & 31;  // block-within-batch (2048/64 = 32)

  // staging: thread covers rows {srow, srow+16, srow+32, srow+48}, 8 floats each
  const int srow = (tid * 8) >> 7;  // 0..15
  const int scol = (tid * 8) & 127;
  const float* encBase = enc + (size_t)r0 * DD;

  float4 lo[4], hi[4];

  auto LOADREGS = [&](int kc) {
    #pragma unroll
    for (int s = 0; s < 4; ++s) {
      const float* p = encBase + (size_t)(srow + s * 16) * DD + kc * CK + scol;
      lo[s] = *(const float4*)p;
      hi[s] = *(const float4*)(p + 4);
    }
  };
  auto WRITE = [&](int kc) {
    #pragma unroll
    for (int s = 0; s < 4; ++s)
      *(bf16x8*)&As[(srow + s * 16) * LDA + kc * CK + scol] = pack8(lo[s], hi[s]);
  };

  // packed-B base: per (j,kg) tile, lane reads 16 B at tile*1024 + lane*16
  const unsigned short* bTile = web + (size_t)(wc * 8) * 16 * 512 + (lane << 3);

  float pp[8], vv[8];
  #pragma unroll
  for (int j = 0; j < 8; ++j) {
    const int col = wc * 128 + j * 16 + c;
    pp[j] = ph[b * AA + col];
    vv[j] = vvec[col];
  }

  f32x4 acc[4][8];
  #pragma unroll
  for (int i = 0; i < 4; ++i)
    #pragma unroll
    for (int j = 0; j < 8; ++j)
      acc[i][j] = (f32x4){0.f, 0.f, 0.f, 0.f};

  // prologue: stage chunk 0
  LOADREGS(0);
  WRITE(0);
  __syncthreads();

  #pragma unroll
  for (int kc = 0; kc < 4; ++kc) {
    if (kc < 3) LOADREGS(kc + 1);              // issue next chunk's loads early

    const unsigned short* aB = &As[c * LDA + kc * CK + quad * 8];
    const int kg0 = kc * (CK / 32);            // k-group base this chunk
    #pragma unroll
    for (int k0 = 0; k0 < CK; k0 += 32) {
      const int kg = kg0 + (k0 >> 5);
      bf16x8 bfr[8];
      #pragma unroll
      for (int j = 0; j < 8; ++j)
        bfr[j] = *(const bf16x8*)(bTile + ((size_t)(j * 16 + kg) << 9));
      bf16x8 af[4];
      #pragma unroll
      for (int i = 0; i < 4; ++i)
        af[i] = *(const bf16x8*)(aB + i * 16 * LDA + k0);
      #pragma unroll
      for (int i = 0; i < 4; ++i)
        #pragma unroll
        for (int j = 0; j < 8; ++j)
          acc[i][j] = __builtin_amdgcn_mfma_f32_16x16x32_bf16(af[i], bfr[j], acc[i][j], 0, 0, 0);
    }

    if (kc < 3) WRITE(kc + 1);                 // pack + ds_write after compute
    __syncthreads();                           // chunk kc+1 visible; no WAR (new cols)
  }

  // scores epilogue: per-row partial = sum_cols v*tanh(acc+ph); C/D: row=quad*4+r, col=c
  #pragma unroll
  for (int i = 0; i < 4; ++i) {
    #pragma unroll
    for (int r = 0; r < 4; ++r) {
      float p = 0.f;
      #pragma unroll
      for (int j = 0; j < 8; ++j)
        p += vv[j] * fast_tanh(acc[i][j][r] + pp[j]);
      p += __shfl_xor(p, 1, 64);
      p += __shfl_xor(p, 2, 64);
      p += __shfl_xor(p, 4, 64);
      p += __shfl_xor(p, 8, 64);
      if (c == 0) sred[wc][i * 16 + quad * 4 + r] = p;
    }
  }
  __syncthreads();

  // finalize scores, apply mask into sfin
  if (tid < RR) {
    float s = sred[0][tid] + sred[1][tid] + sred[2][tid] + sred[3][tid];
    scores[r0 + tid] = s;
    sfin[tid] = (mask[r0 + tid] == 0) ? NEG_INF : s;
  }
  __syncthreads();

  // block max m (one wave over 64 rows)
  if (tid < 64) {
    float v = sfin[tid];
    #pragma unroll
    for (int o = 32; o; o >>= 1) v = fmaxf(v, __shfl_xor(v, o, 64));
    if (tid == 0) mlred[0] = v;
  }
  __syncthreads();
  const float mblk = mlred[0];

  // weights + block sum l (one wave)
  if (tid < 64) {
    float w0 = __expf(sfin[tid] - mblk);
    wgt[tid] = w0;
    float v = w0;
    #pragma unroll
    for (int o = 32; o; o >>= 1) v += __shfl_xor(v, o, 64);
    if (tid == 0) mlred[1] = v;
  }
  __syncthreads();

  // partial context from the LDS bf16 tile: thread t owns columns t and t+256
  #pragma unroll
  for (int cc = 0; cc < 2; ++cc) {
    const int col = tid + cc * 256;
    const unsigned short* colp = &As[col];
    float a0 = 0.f, a1 = 0.f, a2 = 0.f, a3 = 0.f;
    #pragma unroll 4
    for (int r = 0; r < RR; r += 4) {
      a0 += wgt[r]     * bf2f(colp[(size_t)(r    ) * LDA]);
      a1 += wgt[r + 1] * bf2f(colp[(size_t)(r + 1) * LDA]);
      a2 += wgt[r + 2] * bf2f(colp[(size_t)(r + 2) * LDA]);
      a3 += wgt[r + 3] * bf2f(colp[(size_t)(r + 3) * LDA]);
    }
    cpart[((size_t)(b * 32 + blk)) * DD + col] = (a0 + a1) + (a2 + a3);
  }
  if (tid == 0) {
    ml[(b * 32 + blk) * 2]     = mblk;
    ml[(b * 32 + blk) * 2 + 1] = mlred[1];
  }
}

// -------- finalize: masked softmax (alpha) + context combine, one kernel --------
// 64 blocks x 256 threads. Softmax body identical to the verified softmax_kernel.
// Combine: ctx_b = sum_i e^{m_i-M} c_i / sum_i l_i e^{m_i-M} (exact online merge),
// 2 columns per thread.
__global__ __launch_bounds__(256)
void finalize_kernel(const float* __restrict__ scores, const int* __restrict__ mask,
                     const float* __restrict__ cpart, const float* __restrict__ ml,
                     float* __restrict__ alpha, float* __restrict__ ctx) {
  const int b = blockIdx.x, tid = threadIdx.x;
  const int base = b * NN;

  // ---- softmax over N ----
  float vals[8];
  float mx = -3.4e38f;
  #pragma unroll
  for (int i = 0; i < 8; ++i) {
    int n = tid + 256 * i;
    float s = scores[base + n];
    if (mask[base + n] == 0) s = NEG_INF;
    vals[i] = s;
    mx = fmaxf(mx, s);
  }
  #pragma unroll
  for (int o = 32; o; o >>= 1) mx = fmaxf(mx, __shfl_xor(mx, o, 64));
  __shared__ float w4[4];
  if ((tid & 63) == 0) w4[tid >> 6] = mx;
  __syncthreads();
  mx = fmaxf(fmaxf(w4[0], w4[1]), fmaxf(w4[2], w4[3]));
  float sum = 0.f;
  #pragma unroll
  for (int i = 0; i < 8; ++i) { vals[i] = __expf(vals[i] - mx); sum += vals[i]; }
  #pragma unroll
  for (int o = 32; o; o >>= 1) sum += __shfl_xor(sum, o, 64);
  __shared__ float s4[4];
  if ((tid & 63) == 0) s4[tid >> 6] = sum;
  __syncthreads();
  sum = s4[0] + s4[1] + s4[2] + s4[3];
  float inv = 1.f / sum;
  #pragma unroll
  for (int i = 0; i < 8; ++i) alpha[base + tid + 256 * i] = vals[i] * inv;

  // ---- context combine (independent data; barrier only guards mls reuse) ----
  __shared__ float mls[64];
  if (tid < 64) mls[tid] = ml[b * 64 + tid];
  __syncthreads();
  float M = -3.4e38f;
  #pragma unroll
  for (int i = 0; i < 32; ++i) M = fmaxf(M, mls[2 * i]);
  float L = 0.f;
  float acc0 = 0.f, acc1 = 0.f;
  #pragma unroll
  for (int i = 0; i < 32; ++i) {
    float w = __expf(mls[2 * i] - M);
    L += mls[2 * i + 1] * w;
    const float* cp = cpart + ((size_t)(b * 32 + i)) * DD;
    acc0 += w * cp[tid];
    acc1 += w * cp[tid + 256];
  }
  float invL = 1.f / L;
  ctx[b * DD + tid]       = acc0 * invL;
  ctx[b * DD + tid + 256] = acc1 * invL;
}

extern "C" void kernel_launch(void* const* d_in, const int* in_sizes, int n_in,
                              void* d_out, int out_size, void* d_ws, size_t ws_size,
                              hipStream_t stream) {
  const float* h    = (const float*)d_in[0];
  const float* enc  = (const float*)d_in[1];
  const int*   mask = (const int*)d_in[2];
  const float* Wh   = (const float*)d_in[3];
  const float* We   = (const float*)d_in[4];
  const float* v    = (const float*)d_in[5];

  float* out   = (float*)d_out;
  float* ctx   = out;                 // (B, D)
  float* alpha = out + BB * DD;       // (B, N)

  char* w = (char*)d_ws;
  unsigned short* web = (unsigned short*)w;                 // 512 KB (packed tiles)
  float* ph     = (float*)(w + (size_t)AA * DD * 2);        // 128 KB
  float* scores = ph + BB * AA;                             // 512 KB
  float* cpart  = scores + BB * NN;                         // 4 MB (64*32*512)
  float* ml     = cpart + BB * 32 * DD;                     // 16 KB (64*32*2)

  prep_kernel<<<256, 256, 0, stream>>>(We, web, h, Wh, ph);
  scores_ctx_fused<<<(BB * NN) / 64, 256, 0, stream>>>(enc, web, ph, v, mask,
                                                       scores, cpart, ml);
  finalize_kernel<<<BB, 256, 0, stream>>>(scores, mask, cpart, ml, alpha, ctx);
  (void)in_sizes; (void)n_in; (void)out_size; (void)ws_size;
}